// Round 1
// baseline (208.105 us; speedup 1.0000x reference)
//
#include <hip/hip_runtime.h>
#include <stdint.h>

// Workspace byte offsets (all 128B-aligned regions)
#define OFF_W1  0        // 1024*32 u32 = 128 KB packed sign bits of w1 (784 bits + zero pad)
#define OFF_W2  131072   // 128 KB
#define OFF_W3  262144   // 128 KB
#define OFF_WFC 393216   // 10*32 u32 = 1280 B (padded to 2048)
#define OFF_T1  395264   // 1024 int32 popcount thresholds
#define OFF_T2  399360
#define OFF_T3  403456
#define OFF_SFC 407552   // double: mean|wfc|

#define ROWS 16          // batch rows per block in main kernel

// ---------------------------------------------------------------------------
// Prep: pack weight sign bits, compute per-channel integer popcount thresholds
// bit convention: bit=1 <=> value=+1 (w >= 0; sign(0)=+1 per Brevitas)
// dot(h,w) over K elems = K - 2*popc(xor). Layer+BN+sign == (p <= Tint[o]).
// Tint computed in double => sign decisions exact vs infinite precision.
// ---------------------------------------------------------------------------
__global__ __launch_bounds__(256) void bnn_prep(
    const float* __restrict__ w1, const float* __restrict__ b1, const float* __restrict__ g1,
    const float* __restrict__ be1, const float* __restrict__ m1, const float* __restrict__ v1,
    const float* __restrict__ w2, const float* __restrict__ b2, const float* __restrict__ g2,
    const float* __restrict__ be2, const float* __restrict__ m2, const float* __restrict__ v2,
    const float* __restrict__ w3, const float* __restrict__ b3, const float* __restrict__ g3,
    const float* __restrict__ be3, const float* __restrict__ m3, const float* __restrict__ v3,
    const float* __restrict__ wfc,
    uint32_t* __restrict__ ws)
{
    const int t    = threadIdx.x;
    const int lane = t & 63;
    const int wv   = t >> 6;
    const int blk  = blockIdx.x;
    __shared__ double red[4];

    if (blk < 3072) {
        const int l = blk >> 10;      // layer 0..2
        const int o = blk & 1023;     // output channel
        const float *w, *bb, *g, *be, *m, *v;
        int K; uint32_t* Wp; int* T;
        if (l == 0)      { w=w1; bb=b1; g=g1; be=be1; m=m1; v=v1; K=784;  Wp = ws + OFF_W1/4; T = (int*)(ws + OFF_T1/4); }
        else if (l == 1) { w=w2; bb=b2; g=g2; be=be2; m=m2; v=v2; K=1024; Wp = ws + OFF_W2/4; T = (int*)(ws + OFF_T2/4); }
        else             { w=w3; bb=b3; g=g3; be=be3; m=m3; v=v3; K=1024; Wp = ws + OFF_W3/4; T = (int*)(ws + OFF_T3/4); }

        const float* wr = w + (size_t)o * K;
        double s = 0.0;
        #pragma unroll
        for (int iter = 0; iter < 4; ++iter) {
            int idx = iter * 256 + t;
            bool inb = idx < K;
            float wval = inb ? wr[idx] : -1.0f;           // OOB -> bit 0 (zero pad in both operands)
            if (inb) s += fabs((double)wval);
            unsigned long long mask = __ballot(inb && (wval >= 0.0f));
            if (lane == 0)
                *(uint64_t*)(Wp + (size_t)o * 32 + iter * 8 + wv * 2) = mask;
        }
        // wave reduce, then cross-wave via LDS
        #pragma unroll
        for (int off = 32; off > 0; off >>= 1) s += __shfl_down(s, off, 64);
        if (lane == 0) red[wv] = s;
        __syncthreads();
        if (t == 0) {
            double sum = red[0] + red[1] + red[2] + red[3];
            double scale = sum / (double)K;                     // mean|w| per out channel, > 0
            double r = (double)g[o] / sqrt((double)v[o] + 1e-5); // > 0 (g in (0.5,1.5))
            // f = s*scale*r + (b-m)*r + be >= 0  <=>  s >= t
            double tt = (((double)m[o] - (double)bb[o]) * r - (double)be[o]) / (scale * r);
            double C  = ceil(tt);                                // s >= C (s integer, >= inclusive: sign(0)=+1)
            double Td = floor(((double)K - C) * 0.5);            // p <= Td
            Td = fmax(fmin(Td, 100000.0), -1.0);
            T[o] = (int)Td;
        }
    } else {
        // wfc: pack 10 rows of 1024 bits + global mean|wfc| in double
        uint32_t* Wp = ws + OFF_WFC/4;
        double s = 0.0;
        for (int rr = 0; rr < 10; ++rr) {
            const float* wr = wfc + rr * 1024;
            #pragma unroll
            for (int iter = 0; iter < 4; ++iter) {
                int idx = iter * 256 + t;
                float wval = wr[idx];
                s += fabs((double)wval);
                unsigned long long mask = __ballot(wval >= 0.0f);
                if (lane == 0)
                    *(uint64_t*)(Wp + rr * 32 + iter * 8 + wv * 2) = mask;
            }
        }
        #pragma unroll
        for (int off = 32; off > 0; off >>= 1) s += __shfl_down(s, off, 64);
        if (lane == 0) red[wv] = s;
        __syncthreads();
        if (t == 0) {
            *(double*)(ws + OFF_SFC/4) = (red[0] + red[1] + red[2] + red[3]) / 10240.0;
        }
    }
}

// ---------------------------------------------------------------------------
// Main: fully fused 3 binary layers + final FC. Rows are independent, so each
// block carries its 16 rows through all layers via two LDS ping-pong buffers.
// Mapping: lane = output channel; W rows register-resident (2 o's / thread /
// chunk); A row broadcast-read from LDS (conflict-free); __ballot packs the
// next layer's bits.
// ---------------------------------------------------------------------------
__global__ __launch_bounds__(256) void bnn_main(
    const float* __restrict__ x,
    const uint32_t* __restrict__ ws,
    const float* __restrict__ bfc,
    float* __restrict__ out)
{
    __shared__ uint32_t bufA[ROWS][32];
    __shared__ uint32_t bufB[ROWS][32];
    const int t    = threadIdx.x;
    const int lane = t & 63;
    const int wv   = t >> 6;
    const int row0 = blockIdx.x * ROWS;

    // ---- phase 0: pack input bits: +1 <=> 2x-1 >= 0 <=> x >= 0.5 ----
    for (int r = 0; r < ROWS; ++r) {
        const float* xr = x + (size_t)(row0 + r) * 784;
        #pragma unroll
        for (int iter = 0; iter < 4; ++iter) {
            int idx = iter * 256 + t;
            bool bit = (idx < 784) && (xr[idx] >= 0.5f);
            unsigned long long mask = __ballot(bit);
            if (lane == 0)
                *(uint64_t*)(&bufA[r][iter * 8 + wv * 2]) = mask;
        }
    }
    __syncthreads();

    const uint32_t* Wbase[3] = { ws + OFF_W1/4, ws + OFF_W2/4, ws + OFF_W3/4 };
    const int*      Tbase[3] = { (const int*)(ws + OFF_T1/4), (const int*)(ws + OFF_T2/4), (const int*)(ws + OFF_T3/4) };

    uint32_t (*cur)[32] = bufA;
    uint32_t (*nxt)[32] = bufB;

    for (int l = 0; l < 3; ++l) {
        const uint32_t* Wp = Wbase[l];
        const int*      T  = Tbase[l];
        #pragma unroll
        for (int c = 0; c < 2; ++c) {          // 2 chunks of 512 output channels
            const int o0 = c * 512 + t;        // this thread's two channels
            const int o1 = o0 + 256;
            uint32_t W0[32], W1[32];
            const uint4* p0 = (const uint4*)(Wp + (size_t)o0 * 32);
            const uint4* p1 = (const uint4*)(Wp + (size_t)o1 * 32);
            #pragma unroll
            for (int i = 0; i < 8; ++i) { ((uint4*)W0)[i] = p0[i]; ((uint4*)W1)[i] = p1[i]; }
            const int T0 = T[o0];
            const int T1v = T[o1];

            for (int r = 0; r < ROWS; ++r) {
                uint32_t A[32];
                #pragma unroll
                for (int i = 0; i < 8; ++i) ((uint4*)A)[i] = ((const uint4*)cur[r])[i];
                int pa = 0, pb = 0, pc = 0, pd = 0;   // 4 chains for ILP
                #pragma unroll
                for (int i = 0; i < 16; ++i) {
                    pa += __popc(A[i]      ^ W0[i]);
                    pb += __popc(A[i + 16] ^ W0[i + 16]);
                    pc += __popc(A[i]      ^ W1[i]);
                    pd += __popc(A[i + 16] ^ W1[i + 16]);
                }
                unsigned long long m0 = __ballot((pa + pb) <= T0);
                unsigned long long m1 = __ballot((pc + pd) <= T1v);
                if (lane == 0) {
                    // wave wv's 64 lanes cover channels [512c+64wv, +64) -> word 16c+2wv
                    *(uint64_t*)(&nxt[r][c * 16 + wv * 2])     = m0;
                    *(uint64_t*)(&nxt[r][c * 16 + 8 + wv * 2]) = m1;
                }
            }
        }
        __syncthreads();
        uint32_t (*tmp)[32] = cur; cur = nxt; nxt = tmp;
    }

    // ---- final FC: out[b][c] = (1024 - 2p)*scaleFC + bfc[c], exact integer s ----
    const float sfc = (float)(*(const double*)(ws + OFF_SFC/4));
    const uint32_t* Wfc = ws + OFF_WFC/4;
    if (t < ROWS * 10) {
        const int r = t / 10, ch = t % 10;
        const uint32_t* wrow = Wfc + ch * 32;
        int p = 0;
        #pragma unroll
        for (int i = 0; i < 32; ++i) p += __popc(cur[r][i] ^ wrow[i]);
        const int s = 1024 - 2 * p;
        out[(size_t)(row0 + r) * 10 + ch] = (float)s * sfc + bfc[ch];
    }
}

extern "C" void kernel_launch(void* const* d_in, const int* in_sizes, int n_in,
                              void* d_out, int out_size, void* d_ws, size_t ws_size,
                              hipStream_t stream) {
    const float* x   = (const float*)d_in[0];
    const float* w1  = (const float*)d_in[1];
    const float* b1  = (const float*)d_in[2];
    const float* g1  = (const float*)d_in[3];
    const float* be1 = (const float*)d_in[4];
    const float* m1  = (const float*)d_in[5];
    const float* v1  = (const float*)d_in[6];
    const float* w2  = (const float*)d_in[7];
    const float* b2  = (const float*)d_in[8];
    const float* g2  = (const float*)d_in[9];
    const float* be2 = (const float*)d_in[10];
    const float* m2  = (const float*)d_in[11];
    const float* v2  = (const float*)d_in[12];
    const float* w3  = (const float*)d_in[13];
    const float* b3  = (const float*)d_in[14];
    const float* g3  = (const float*)d_in[15];
    const float* be3 = (const float*)d_in[16];
    const float* m3  = (const float*)d_in[17];
    const float* v3  = (const float*)d_in[18];
    const float* wfc = (const float*)d_in[19];
    const float* bfc = (const float*)d_in[20];
    uint32_t* ws = (uint32_t*)d_ws;
    float* out = (float*)d_out;

    bnn_prep<<<3073, 256, 0, stream>>>(w1, b1, g1, be1, m1, v1,
                                       w2, b2, g2, be2, m2, v2,
                                       w3, b3, g3, be3, m3, v3,
                                       wfc, ws);
    bnn_main<<<8192 / ROWS, 256, 0, stream>>>(x, ws, bfc, out);
}